// Round 16
// baseline (207.414 us; speedup 1.0000x reference)
//
#include <hip/hip_runtime.h>
#include <hip/hip_bf16.h>
#include <stdint.h>

#define TOKS  2048
#define HID   2048
#define ITR   1024
#define NEXP  8
#define NROWS 4096   // TOKS * TOP_K

typedef __attribute__((ext_vector_type(4))) float f32x4;
typedef __attribute__((ext_vector_type(8))) __bf16 bf16x8;
typedef __attribute__((ext_vector_type(8))) unsigned short u16x8;
typedef __attribute__((ext_vector_type(4))) unsigned short u16x4;

__device__ __forceinline__ unsigned short f2bf(float f) {
    union { float f; uint32_t u; } c; c.f = f;
    return (unsigned short)((c.u + 0x7FFFu + ((c.u >> 16) & 1u)) >> 16);
}

// async global->LDS, 16B per lane. LDS dest = wave-uniform base + lane*16 (HW).
__device__ __forceinline__ void gll16(const void* g, void* l) {
    __builtin_amdgcn_global_load_lds(
        (const __attribute__((address_space(1))) unsigned int*)g,
        (__attribute__((address_space(3))) unsigned int*)l,
        16, 0, 0);
}

// ---------------- router: logits top-2 + bf16 copy of x ----------------
__global__ __launch_bounds__(64) void router_kernel(const float* __restrict__ x,
                                                    const float* __restrict__ gw,
                                                    unsigned short* __restrict__ xb,
                                                    int* __restrict__ topk_id,
                                                    float* __restrict__ topk_w) {
    const int t = blockIdx.x;
    const int lane = threadIdx.x;
    float acc[NEXP];
#pragma unroll
    for (int e = 0; e < NEXP; ++e) acc[e] = 0.f;
    const float* xr = x + (size_t)t * HID;
    unsigned short* xbr = xb + (size_t)t * HID;
    for (int s4 = lane; s4 < HID / 4; s4 += 64) {
        const f32x4 xv = *(const f32x4*)(xr + s4 * 4);
        u16x4 o;
#pragma unroll
        for (int j = 0; j < 4; ++j) o[j] = f2bf(xv[j]);
        *(u16x4*)(xbr + s4 * 4) = o;
#pragma unroll
        for (int e = 0; e < NEXP; ++e) {
            const f32x4 gv = *(const f32x4*)(gw + e * HID + s4 * 4);
            acc[e] += xv[0] * gv[0] + xv[1] * gv[1] + xv[2] * gv[2] + xv[3] * gv[3];
        }
    }
#pragma unroll
    for (int e = 0; e < NEXP; ++e) {
        float v = acc[e];
        for (int off = 32; off > 0; off >>= 1) v += __shfl_down(v, off, 64);
        acc[e] = v;
    }
    if (lane == 0) {
        float m0 = -1e30f, m1 = -1e30f; int i0 = 0, i1 = 0;
#pragma unroll
        for (int e = 0; e < NEXP; ++e) {
            float v = acc[e];
            if (v > m0) { m1 = m0; i1 = i0; m0 = v; i0 = e; }
            else if (v > m1) { m1 = v; i1 = e; }
        }
        float w0 = 1.f / (1.f + expf(m1 - m0));
        topk_id[t * 2] = i0; topk_id[t * 2 + 1] = i1;
        topk_w[t * 2] = w0;  topk_w[t * 2 + 1] = 1.f - w0;
    }
}

// ---------------- deterministic single-block sort-by-expert ----------------
__global__ __launch_bounds__(512) void sort_kernel(const int* __restrict__ topk_id,
                                                   const float* __restrict__ topk_w,
                                                   int* __restrict__ sorted_tok,
                                                   float* __restrict__ row_w,
                                                   int* __restrict__ offsets,
                                                   int* __restrict__ counts) {
    __shared__ int sc[512 * NEXP];
    __shared__ int base[NEXP + 1];
    const int t = threadIdx.x;
    int ids[8];
    int* myrow = &sc[t * NEXP];
#pragma unroll
    for (int e = 0; e < NEXP; ++e) myrow[e] = 0;
#pragma unroll
    for (int j = 0; j < 8; ++j) { ids[j] = topk_id[t * 8 + j]; myrow[ids[j]]++; }
    __syncthreads();
    for (int d = 1; d < 512; d <<= 1) {
        int add[NEXP];
        const bool act = (t >= d);
#pragma unroll
        for (int e = 0; e < NEXP; ++e) add[e] = act ? sc[(t - d) * NEXP + e] : 0;
        __syncthreads();
        if (act) {
#pragma unroll
            for (int e = 0; e < NEXP; ++e) sc[t * NEXP + e] += add[e];
        }
        __syncthreads();
    }
    if (t == 0) {
        int s = 0;
        for (int e = 0; e < NEXP; ++e) {
            const int tot = sc[511 * NEXP + e];
            base[e] = s; offsets[e] = s; counts[e] = tot; s += tot;
        }
        base[NEXP] = s; offsets[NEXP] = s;
    }
    __syncthreads();
    int own[NEXP];
#pragma unroll
    for (int e = 0; e < NEXP; ++e) {
        int c = 0;
#pragma unroll
        for (int j = 0; j < 8; ++j) c += (ids[j] == e) ? 1 : 0;
        own[e] = c;
    }
#pragma unroll
    for (int e = 0; e < NEXP; ++e) myrow[e] = base[e] + myrow[e] - own[e];
#pragma unroll
    for (int j = 0; j < 8; ++j) {
        const int p = t * 8 + j;
        const int pos = myrow[ids[j]]++;
        sorted_tok[pos] = p >> 1;
        row_w[pos] = topk_w[p];
    }
}

// ---------------- GEMM1: gathered xb(bf16) @ ws(fp32,direct)^T, fused SiLU*up ----
// B staged as fp32 via gll16 (2 calls/thread/stage), converted to bf16 on
// fragment read. A path unchanged. vmcnt(3) = 3 loads/stage. LDS 72 KB.
__global__ __launch_bounds__(512) void gemm1_kernel(const float* __restrict__ W,
                                                    const unsigned short* __restrict__ Xb,
                                                    const int* __restrict__ offsets,
                                                    const int* __restrict__ counts,
                                                    const int* __restrict__ sorted_tok,
                                                    unsigned short* __restrict__ act) {
    const int b = blockIdx.x;
    const int e = b & 7;
    const int r = b >> 3;
    const int mt = r >> 4;        // mt outer (dense live-block packing)
    const int nt = r & 15;        // nt inner
    const int cnt = counts[e];
    if (mt * 128 >= cnt) return;
    const int offs = offsets[e];
    const int tid = threadIdx.x, lane = tid & 63, wid = tid >> 6;
    const int wr = wid >> 2, wc = wid & 3;

    __shared__ unsigned short sA[3][128 * 32];   // bf16 A, 8 KB/buf
    __shared__ float sBf[3][128 * 32];           // fp32 B, 16 KB/buf

    // ---- A staging (unchanged): row tid>>2, 16B-chunk swizzle ----
    const int srow = tid >> 2;
    const int swz = (((tid & 3) ^ (srow & 3))) * 8;
    int ar = mt * 128 + srow;
    if (ar >= cnt) ar = cnt - 1;
    const int tok = sorted_tok[offs + ar];
    const unsigned short* aSrc = Xb + (size_t)tok * HID + swz;
    const int ldsA = wid * 16 * 32;

    // ---- B staging: fp32, 2 gll16/thread, 32B-chunk XOR swizzle on source ----
    const int l8 = lane & 7;            // 16B slot within 128B row
    const int rr = lane >> 3;           // row within 8-row call group
    const int foff = (((l8 >> 1) ^ (rr & 3)) * 8) + (l8 & 1) * 4;  // float offset
    const int R1 = wid * 16 + rr;
    const int R2 = R1 + 8;
    const int g1row = (R1 < 64) ? (nt * 64 + R1) : (ITR + nt * 64 + (R1 - 64));
    const int g2row = (R2 < 64) ? (nt * 64 + R2) : (ITR + nt * 64 + (R2 - 64));
    const float* bSrc1 = W + ((size_t)e * 2 * ITR + g1row) * HID + foff;
    const float* bSrc2 = W + ((size_t)e * 2 * ITR + g2row) * HID + foff;
    const int ldsB1 = (wid * 16) * 32;       // float index
    const int ldsB2 = (wid * 16 + 8) * 32;

    f32x4 accg[4], accu[4];
#pragma unroll
    for (int i = 0; i < 4; ++i) {
        accg[i] = (f32x4){0.f, 0.f, 0.f, 0.f};
        accu[i] = (f32x4){0.f, 0.f, 0.f, 0.f};
    }

#define G1_STAGE(ks) do {                                  \
        const int k0_ = (ks) * 32;                         \
        gll16(aSrc + k0_, sA[(ks) % 3] + ldsA);            \
        gll16(bSrc1 + k0_, sBf[(ks) % 3] + ldsB1);         \
        gll16(bSrc2 + k0_, sBf[(ks) % 3] + ldsB2);         \
    } while (0)

    G1_STAGE(0);
    G1_STAGE(1);

    const int fr = lane & 15, fq = lane >> 4;
    const int sfo = (fq ^ (fr & 3)) * 8;         // A read swizzle (bf16, 16B chunks)
    const int slot32 = fq ^ (fr & 3);            // B read swizzle (fp32, 32B chunks)
    const int NS = HID / 32;
    for (int ks = 0; ks < NS; ++ks) {
        const int cur = ks % 3;
        if (ks == NS - 1) asm volatile("s_waitcnt vmcnt(0)" ::: "memory");
        else              asm volatile("s_waitcnt vmcnt(3)" ::: "memory");
        __builtin_amdgcn_s_barrier();
        asm volatile("" ::: "memory");
        if (ks + 2 < NS) G1_STAGE(ks + 2);
        bf16x8 af[4];
#pragma unroll
        for (int mi = 0; mi < 4; ++mi)
            af[mi] = *(const bf16x8*)&sA[cur][(wr * 64 + mi * 16 + fr) * 32 + sfo];
        const float* pg = &sBf[cur][(wc * 16 + fr) * 32 + slot32 * 8];
        const float* pu = &sBf[cur][(64 + wc * 16 + fr) * 32 + slot32 * 8];
        const f32x4 g0 = *(const f32x4*)pg, g1 = *(const f32x4*)(pg + 4);
        const f32x4 u0 = *(const f32x4*)pu, u1 = *(const f32x4*)(pu + 4);
        bf16x8 bg, bu;
#pragma unroll
        for (int j = 0; j < 4; ++j) {
            bg[j] = (__bf16)g0[j]; bg[4 + j] = (__bf16)g1[j];
            bu[j] = (__bf16)u0[j]; bu[4 + j] = (__bf16)u1[j];
        }
        __builtin_amdgcn_s_setprio(1);
#pragma unroll
        for (int mi = 0; mi < 4; ++mi) {
            accg[mi] = __builtin_amdgcn_mfma_f32_16x16x32_bf16(af[mi], bg, accg[mi], 0, 0, 0);
            accu[mi] = __builtin_amdgcn_mfma_f32_16x16x32_bf16(af[mi], bu, accu[mi], 0, 0, 0);
        }
        __builtin_amdgcn_s_setprio(0);
        asm volatile("" ::: "memory");
    }
#undef G1_STAGE

#pragma unroll
    for (int mi = 0; mi < 4; ++mi) {
#pragma unroll
        for (int j = 0; j < 4; ++j) {
            const int gr = mt * 128 + wr * 64 + mi * 16 + fq * 4 + j;
            if (gr < cnt) {
                const float g = accg[mi][j], u = accu[mi][j];
                const float s = g / (1.f + expf(-g));
                act[(size_t)(offs + gr) * ITR + nt * 64 + wc * 16 + fr] = f2bf(s * u);
            }
        }
    }
}

// ---------------- GEMM2: actb(bf16) @ w2s(fp32,direct)^T, weighted scatter-add ----
__global__ __launch_bounds__(512) void gemm2_kernel(const float* __restrict__ W2,
                                                    const unsigned short* __restrict__ actb,
                                                    const int* __restrict__ offsets,
                                                    const int* __restrict__ counts,
                                                    const int* __restrict__ sorted_tok,
                                                    const float* __restrict__ row_w,
                                                    float* __restrict__ out) {
    const int b = blockIdx.x;
    const int e = b & 7;
    const int r = b >> 3;
    const int mt = r >> 4;
    const int nt = r & 15;
    const int cnt = counts[e];
    if (mt * 128 >= cnt) return;
    const int offs = offsets[e];
    const int tid = threadIdx.x, lane = tid & 63, wid = tid >> 6;
    const int wr = wid >> 2, wc = wid & 3;

    __shared__ unsigned short sA[3][128 * 32];
    __shared__ float sBf[3][128 * 32];

    const int srow = tid >> 2;
    const int swz = (((tid & 3) ^ (srow & 3))) * 8;
    int ar = mt * 128 + srow;
    if (ar >= cnt) ar = cnt - 1;
    const unsigned short* aSrc = actb + (size_t)(offs + ar) * ITR + swz;
    const int ldsA = wid * 16 * 32;

    const int l8 = lane & 7;
    const int rr = lane >> 3;
    const int foff = (((l8 >> 1) ^ (rr & 3)) * 8) + (l8 & 1) * 4;
    const int R1 = wid * 16 + rr;
    const int R2 = R1 + 8;
    const float* bSrc1 = W2 + ((size_t)e * HID + nt * 128 + R1) * ITR + foff;
    const float* bSrc2 = W2 + ((size_t)e * HID + nt * 128 + R2) * ITR + foff;
    const int ldsB1 = (wid * 16) * 32;
    const int ldsB2 = (wid * 16 + 8) * 32;

    f32x4 acc[4][2];
#pragma unroll
    for (int i = 0; i < 4; ++i)
#pragma unroll
        for (int j = 0; j < 2; ++j) acc[i][j] = (f32x4){0.f, 0.f, 0.f, 0.f};

#define G2_STAGE(ks) do {                                  \
        const int k0_ = (ks) * 32;                         \
        gll16(aSrc + k0_, sA[(ks) % 3] + ldsA);            \
        gll16(bSrc1 + k0_, sBf[(ks) % 3] + ldsB1);         \
        gll16(bSrc2 + k0_, sBf[(ks) % 3] + ldsB2);         \
    } while (0)

    G2_STAGE(0);
    G2_STAGE(1);

    const int fr = lane & 15, fq = lane >> 4;
    const int sfo = (fq ^ (fr & 3)) * 8;
    const int slot32 = fq ^ (fr & 3);
    const int NS = ITR / 32;
    for (int ks = 0; ks < NS; ++ks) {
        const int cur = ks % 3;
        if (ks == NS - 1) asm volatile("s_waitcnt vmcnt(0)" ::: "memory");
        else              asm volatile("s_waitcnt vmcnt(3)" ::: "memory");
        __builtin_amdgcn_s_barrier();
        asm volatile("" ::: "memory");
        if (ks + 2 < NS) G2_STAGE(ks + 2);
        bf16x8 af[4];
#pragma unroll
        for (int mi = 0; mi < 4; ++mi)
            af[mi] = *(const bf16x8*)&sA[cur][(wr * 64 + mi * 16 + fr) * 32 + sfo];
        bf16x8 bfv[2];
#pragma unroll
        for (int ni = 0; ni < 2; ++ni) {
            const float* pb = &sBf[cur][(wc * 32 + ni * 16 + fr) * 32 + slot32 * 8];
            const f32x4 v0 = *(const f32x4*)pb, v1 = *(const f32x4*)(pb + 4);
#pragma unroll
            for (int j = 0; j < 4; ++j) { bfv[ni][j] = (__bf16)v0[j]; bfv[ni][4 + j] = (__bf16)v1[j]; }
        }
        __builtin_amdgcn_s_setprio(1);
#pragma unroll
        for (int mi = 0; mi < 4; ++mi)
#pragma unroll
            for (int ni = 0; ni < 2; ++ni)
                acc[mi][ni] = __builtin_amdgcn_mfma_f32_16x16x32_bf16(af[mi], bfv[ni], acc[mi][ni], 0, 0, 0);
        __builtin_amdgcn_s_setprio(0);
        asm volatile("" ::: "memory");
    }
#undef G2_STAGE

#pragma unroll
    for (int mi = 0; mi < 4; ++mi) {
#pragma unroll
        for (int j = 0; j < 4; ++j) {
            const int gr = mt * 128 + wr * 64 + mi * 16 + fq * 4 + j;
            if (gr < cnt) {
                const int pos = offs + gr;
                const int t = sorted_tok[pos];
                const float w = row_w[pos];
#pragma unroll
                for (int ni = 0; ni < 2; ++ni) {
                    const int col = nt * 128 + wc * 32 + ni * 16 + fr;
                    atomicAdd(&out[(size_t)t * HID + col], w * acc[mi][ni][j]);
                }
            }
        }
    }
}

extern "C" void kernel_launch(void* const* d_in, const int* in_sizes, int n_in,
                              void* d_out, int out_size, void* d_ws, size_t ws_size,
                              hipStream_t stream) {
    const float* x   = (const float*)d_in[0];
    const float* gw  = (const float*)d_in[1];
    const float* ws  = (const float*)d_in[2];
    const float* w2s = (const float*)d_in[3];
    float* out = (float*)d_out;

    // ---- workspace layout (disjoint; ~17 MiB total) ----
    char* wsb = (char*)d_ws;
    int*   counts     = (int*)(wsb + 0);
    int*   offsets    = (int*)(wsb + 256);
    int*   topk_id    = (int*)(wsb + 4096);
    float* topk_w     = (float*)(wsb + 20480);
    int*   sorted_tok = (int*)(wsb + 36864);
    float* row_w      = (float*)(wsb + 53248);
    unsigned short* xb   = (unsigned short*)(wsb + (1u << 20));   // 8 MiB
    unsigned short* actb = (unsigned short*)(wsb + 9437184);      // 8 MiB

    hipMemsetAsync(out, 0, (size_t)out_size * sizeof(float), stream);
    router_kernel<<<TOKS, 64, 0, stream>>>(x, gw, xb, topk_id, topk_w);
    sort_kernel<<<1, 512, 0, stream>>>(topk_id, topk_w, sorted_tok, row_w, offsets, counts);
    gemm1_kernel<<<2048, 512, 0, stream>>>(ws, xb, offsets, counts, sorted_tok, actb);
    gemm2_kernel<<<2048, 512, 0, stream>>>(w2s, actb, offsets, counts, sorted_tok, row_w, out);
}

// Round 17
// 179.278 us; speedup vs baseline: 1.1569x; 1.1569x over previous
//
#include <hip/hip_runtime.h>
#include <hip/hip_bf16.h>
#include <stdint.h>

#define TOKS  2048
#define HID   2048
#define ITR   1024
#define NEXP  8
#define NROWS 4096   // TOKS * TOP_K

typedef __attribute__((ext_vector_type(4))) float f32x4;
typedef __attribute__((ext_vector_type(8))) __bf16 bf16x8;
typedef __attribute__((ext_vector_type(8))) unsigned short u16x8;
typedef __attribute__((ext_vector_type(4))) unsigned short u16x4;

__device__ __forceinline__ unsigned short f2bf(float f) {
    union { float f; uint32_t u; } c; c.f = f;
    return (unsigned short)((c.u + 0x7FFFu + ((c.u >> 16) & 1u)) >> 16);
}

// async global->LDS, 16B per lane. LDS dest = wave-uniform base + lane*16 (HW).
__device__ __forceinline__ void gll16(const unsigned short* g, unsigned short* l) {
    __builtin_amdgcn_global_load_lds(
        (const __attribute__((address_space(1))) unsigned int*)g,
        (__attribute__((address_space(3))) unsigned int*)l,
        16, 0, 0);
}

// ---- prep: cvt ws + cvt w2s (PER-INSTRUCTION coalesced: one f32x4/lane/iter,
// adjacent lanes -> adjacent 16B) + router on wave 0 of first 2048 blocks ----
#define NCA ((NEXP * 2 * ITR * HID) / 4)   // 8388608 f32x4 chunks (ws)
#define NCB ((NEXP * HID * ITR) / 4)       // 4194304 f32x4 chunks (w2s)
__global__ __launch_bounds__(256) void prep_kernel(const float* __restrict__ ws,
                                                   const float* __restrict__ w2s,
                                                   const float* __restrict__ x,
                                                   const float* __restrict__ gw,
                                                   unsigned short* __restrict__ da,
                                                   unsigned short* __restrict__ db,
                                                   unsigned short* __restrict__ xb,
                                                   int* __restrict__ topk_id,
                                                   float* __restrict__ topk_w) {
    const int tid = threadIdx.x;

    // ---- router: wave 0 of blocks 0..2047 handles token t = blockIdx.x ----
    if (blockIdx.x < TOKS && tid < 64) {
        const int t = blockIdx.x;
        const int lane = tid;
        float acc[NEXP];
#pragma unroll
        for (int e = 0; e < NEXP; ++e) acc[e] = 0.f;
        const float* xr = x + (size_t)t * HID;
        unsigned short* xbr = xb + (size_t)t * HID;
        for (int s4 = lane; s4 < HID / 4; s4 += 64) {
            const f32x4 xv = *(const f32x4*)(xr + s4 * 4);
            u16x4 o;
#pragma unroll
            for (int j = 0; j < 4; ++j) o[j] = f2bf(xv[j]);
            *(u16x4*)(xbr + s4 * 4) = o;
#pragma unroll
            for (int e = 0; e < NEXP; ++e) {
                const f32x4 gv = *(const f32x4*)(gw + e * HID + s4 * 4);
                acc[e] += xv[0] * gv[0] + xv[1] * gv[1] + xv[2] * gv[2] + xv[3] * gv[3];
            }
        }
#pragma unroll
        for (int e = 0; e < NEXP; ++e) {
            float v = acc[e];
            for (int off = 32; off > 0; off >>= 1) v += __shfl_down(v, off, 64);
            acc[e] = v;
        }
        if (lane == 0) {
            float m0 = -1e30f, m1 = -1e30f; int i0 = 0, i1 = 0;
#pragma unroll
            for (int e = 0; e < NEXP; ++e) {
                float v = acc[e];
                if (v > m0) { m1 = m0; i1 = i0; m0 = v; i0 = e; }
                else if (v > m1) { m1 = v; i1 = e; }
            }
            float w0 = 1.f / (1.f + expf(m1 - m0));
            topk_id[t * 2] = i0; topk_id[t * 2 + 1] = i1;
            topk_w[t * 2] = w0;  topk_w[t * 2 + 1] = 1.f - w0;
        }
    }

    // ---- weight conversion: lane-contiguous f32x4 chunks, grid-stride ----
    const int NC = NCA + NCB;
    const int stride = gridDim.x * 256;
    for (int i = blockIdx.x * 256 + tid; i < NC; i += stride) {
        const float* s; unsigned short* d; int k;
        if (i < NCA) { s = ws; d = da; k = i; }
        else         { s = w2s; d = db; k = i - NCA; }
        const f32x4 v = *(const f32x4*)(s + (size_t)k * 4);
        u16x4 o;
#pragma unroll
        for (int j = 0; j < 4; ++j) o[j] = f2bf(v[j]);
        *(u16x4*)(d + (size_t)k * 4) = o;
    }
}

// ---------------- deterministic single-block sort-by-expert ----------------
__global__ __launch_bounds__(512) void sort_kernel(const int* __restrict__ topk_id,
                                                   const float* __restrict__ topk_w,
                                                   int* __restrict__ sorted_tok,
                                                   float* __restrict__ row_w,
                                                   int* __restrict__ offsets,
                                                   int* __restrict__ counts) {
    __shared__ int sc[512 * NEXP];
    __shared__ int base[NEXP + 1];
    const int t = threadIdx.x;
    int ids[8];
    int* myrow = &sc[t * NEXP];
#pragma unroll
    for (int e = 0; e < NEXP; ++e) myrow[e] = 0;
#pragma unroll
    for (int j = 0; j < 8; ++j) { ids[j] = topk_id[t * 8 + j]; myrow[ids[j]]++; }
    __syncthreads();
    for (int d = 1; d < 512; d <<= 1) {
        int add[NEXP];
        const bool act = (t >= d);
#pragma unroll
        for (int e = 0; e < NEXP; ++e) add[e] = act ? sc[(t - d) * NEXP + e] : 0;
        __syncthreads();
        if (act) {
#pragma unroll
            for (int e = 0; e < NEXP; ++e) sc[t * NEXP + e] += add[e];
        }
        __syncthreads();
    }
    if (t == 0) {
        int s = 0;
        for (int e = 0; e < NEXP; ++e) {
            const int tot = sc[511 * NEXP + e];
            base[e] = s; offsets[e] = s; counts[e] = tot; s += tot;
        }
        base[NEXP] = s; offsets[NEXP] = s;
    }
    __syncthreads();
    int own[NEXP];
#pragma unroll
    for (int e = 0; e < NEXP; ++e) {
        int c = 0;
#pragma unroll
        for (int j = 0; j < 8; ++j) c += (ids[j] == e) ? 1 : 0;
        own[e] = c;
    }
#pragma unroll
    for (int e = 0; e < NEXP; ++e) myrow[e] = base[e] + myrow[e] - own[e];
#pragma unroll
    for (int j = 0; j < 8; ++j) {
        const int p = t * 8 + j;
        const int pos = myrow[ids[j]]++;
        sorted_tok[pos] = p >> 1;
        row_w[pos] = topk_w[p];
    }
}

// ---------------- GEMM1: gathered xb @ wsb[e]^T, fused SiLU*up ----------------
// XCD-affine (e = b&7); mt OUTER (dense live-block packing); bf16 gll16 staging,
// triple-buffer, counted vmcnt(2). (R11-proven config, no embedded cvt.)
__global__ __launch_bounds__(512) void gemm1_kernel(const unsigned short* __restrict__ Wb,
                                                    const unsigned short* __restrict__ Xb,
                                                    const int* __restrict__ offsets,
                                                    const int* __restrict__ counts,
                                                    const int* __restrict__ sorted_tok,
                                                    unsigned short* __restrict__ act) {
    const int b = blockIdx.x;
    const int e = b & 7;
    const int r = b >> 3;
    const int mt = r >> 4;        // mt outer (dense live-block packing)
    const int nt = r & 15;        // nt inner
    const int cnt = counts[e];
    if (mt * 128 >= cnt) return;
    const int offs = offsets[e];
    const int tid = threadIdx.x, lane = tid & 63, wid = tid >> 6;
    const int wr = wid >> 2, wc = wid & 3;

    __shared__ unsigned short sA[3][128 * 32];
    __shared__ unsigned short sB[3][128 * 32];

    const int srow = tid >> 2;
    const int swz = (((tid & 3) ^ (srow & 3))) * 8;
    int ar = mt * 128 + srow;
    if (ar >= cnt) ar = cnt - 1;
    const int tok = sorted_tok[offs + ar];
    const unsigned short* aSrc = Xb + (size_t)tok * HID + swz;
    const unsigned short* wBase = Wb + (size_t)e * (2 * ITR) * HID;
    const int wrow = (srow < 64) ? (nt * 64 + srow) : (ITR + nt * 64 + (srow - 64));
    const unsigned short* bSrc = wBase + (size_t)wrow * HID + swz;
    const int ldsOff = wid * 16 * 32;

    f32x4 accg[4], accu[4];
#pragma unroll
    for (int i = 0; i < 4; ++i) {
        accg[i] = (f32x4){0.f, 0.f, 0.f, 0.f};
        accu[i] = (f32x4){0.f, 0.f, 0.f, 0.f};
    }

#define G1_STAGE(ks) do {                                  \
        const int k0_ = (ks) * 32;                         \
        gll16(aSrc + k0_, sA[(ks) % 3] + ldsOff);          \
        gll16(bSrc + k0_, sB[(ks) % 3] + ldsOff);          \
    } while (0)

    G1_STAGE(0);
    G1_STAGE(1);

    const int fr = lane & 15, fq = lane >> 4;
    const int sfo = (fq ^ (fr & 3)) * 8;
    const int NS = HID / 32;
    for (int ks = 0; ks < NS; ++ks) {
        const int cur = ks % 3;
        if (ks == NS - 1) asm volatile("s_waitcnt vmcnt(0)" ::: "memory");
        else              asm volatile("s_waitcnt vmcnt(2)" ::: "memory");
        __builtin_amdgcn_s_barrier();
        asm volatile("" ::: "memory");
        if (ks + 2 < NS) G1_STAGE(ks + 2);
        bf16x8 af[4], bg, bu;
#pragma unroll
        for (int mi = 0; mi < 4; ++mi)
            af[mi] = *(const bf16x8*)&sA[cur][(wr * 64 + mi * 16 + fr) * 32 + sfo];
        bg = *(const bf16x8*)&sB[cur][(wc * 16 + fr) * 32 + sfo];
        bu = *(const bf16x8*)&sB[cur][(64 + wc * 16 + fr) * 32 + sfo];
        __builtin_amdgcn_s_setprio(1);
#pragma unroll
        for (int mi = 0; mi < 4; ++mi) {
            accg[mi] = __builtin_amdgcn_mfma_f32_16x16x32_bf16(af[mi], bg, accg[mi], 0, 0, 0);
            accu[mi] = __builtin_amdgcn_mfma_f32_16x16x32_bf16(af[mi], bu, accu[mi], 0, 0, 0);
        }
        __builtin_amdgcn_s_setprio(0);
        asm volatile("" ::: "memory");
    }
#undef G1_STAGE

#pragma unroll
    for (int mi = 0; mi < 4; ++mi) {
#pragma unroll
        for (int j = 0; j < 4; ++j) {
            const int gr = mt * 128 + wr * 64 + mi * 16 + fq * 4 + j;
            if (gr < cnt) {
                const float g = accg[mi][j], u = accu[mi][j];
                const float s = g / (1.f + expf(-g));
                act[(size_t)(offs + gr) * ITR + nt * 64 + wc * 16 + fr] = f2bf(s * u);
            }
        }
    }
}

// ---------------- GEMM2: actb @ w2b[e]^T, fused weighted scatter-add ----------------
__global__ __launch_bounds__(512) void gemm2_kernel(const unsigned short* __restrict__ W2b,
                                                    const unsigned short* __restrict__ actb,
                                                    const int* __restrict__ offsets,
                                                    const int* __restrict__ counts,
                                                    const int* __restrict__ sorted_tok,
                                                    const float* __restrict__ row_w,
                                                    float* __restrict__ out) {
    const int b = blockIdx.x;
    const int e = b & 7;
    const int r = b >> 3;
    const int mt = r >> 4;        // mt outer
    const int nt = r & 15;        // nt inner
    const int cnt = counts[e];
    if (mt * 128 >= cnt) return;
    const int offs = offsets[e];
    const int tid = threadIdx.x, lane = tid & 63, wid = tid >> 6;
    const int wr = wid >> 2, wc = wid & 3;

    __shared__ unsigned short sA[3][128 * 32];
    __shared__ unsigned short sB[3][128 * 32];

    const int srow = tid >> 2;
    const int swz = (((tid & 3) ^ (srow & 3))) * 8;
    int ar = mt * 128 + srow;
    if (ar >= cnt) ar = cnt - 1;
    const unsigned short* aSrc = actb + (size_t)(offs + ar) * ITR + swz;
    const unsigned short* bSrc = W2b + ((size_t)e * HID + nt * 128 + srow) * ITR + swz;
    const int ldsOff = wid * 16 * 32;

    f32x4 acc[4][2];
#pragma unroll
    for (int i = 0; i < 4; ++i)
#pragma unroll
        for (int j = 0; j < 2; ++j) acc[i][j] = (f32x4){0.f, 0.f, 0.f, 0.f};

#define G2_STAGE(ks) do {                                  \
        const int k0_ = (ks) * 32;                         \
        gll16(aSrc + k0_, sA[(ks) % 3] + ldsOff);          \
        gll16(bSrc + k0_, sB[(ks) % 3] + ldsOff);          \
    } while (0)

    G2_STAGE(0);
    G2_STAGE(1);

    const int fr = lane & 15, fq = lane >> 4;
    const int sfo = (fq ^ (fr & 3)) * 8;
    const int NS = ITR / 32;
    for (int ks = 0; ks < NS; ++ks) {
        const int cur = ks % 3;
        if (ks == NS - 1) asm volatile("s_waitcnt vmcnt(0)" ::: "memory");
        else              asm volatile("s_waitcnt vmcnt(2)" ::: "memory");
        __builtin_amdgcn_s_barrier();
        asm volatile("" ::: "memory");
        if (ks + 2 < NS) G2_STAGE(ks + 2);
        bf16x8 af[4], bfv[2];
#pragma unroll
        for (int mi = 0; mi < 4; ++mi)
            af[mi] = *(const bf16x8*)&sA[cur][(wr * 64 + mi * 16 + fr) * 32 + sfo];
#pragma unroll
        for (int ni = 0; ni < 2; ++ni)
            bfv[ni] = *(const bf16x8*)&sB[cur][(wc * 32 + ni * 16 + fr) * 32 + sfo];
        __builtin_amdgcn_s_setprio(1);
#pragma unroll
        for (int mi = 0; mi < 4; ++mi)
#pragma unroll
            for (int ni = 0; ni < 2; ++ni)
                acc[mi][ni] = __builtin_amdgcn_mfma_f32_16x16x32_bf16(af[mi], bfv[ni], acc[mi][ni], 0, 0, 0);
        __builtin_amdgcn_s_setprio(0);
        asm volatile("" ::: "memory");
    }
#undef G2_STAGE

#pragma unroll
    for (int mi = 0; mi < 4; ++mi) {
#pragma unroll
        for (int j = 0; j < 4; ++j) {
            const int gr = mt * 128 + wr * 64 + mi * 16 + fq * 4 + j;
            if (gr < cnt) {
                const int pos = offs + gr;
                const int t = sorted_tok[pos];
                const float w = row_w[pos];
#pragma unroll
                for (int ni = 0; ni < 2; ++ni) {
                    const int col = nt * 128 + wc * 32 + ni * 16 + fr;
                    atomicAdd(&out[(size_t)t * HID + col], w * acc[mi][ni][j]);
                }
            }
        }
    }
}

extern "C" void kernel_launch(void* const* d_in, const int* in_sizes, int n_in,
                              void* d_out, int out_size, void* d_ws, size_t ws_size,
                              hipStream_t stream) {
    const float* x   = (const float*)d_in[0];
    const float* gw  = (const float*)d_in[1];
    const float* ws  = (const float*)d_in[2];
    const float* w2s = (const float*)d_in[3];
    float* out = (float*)d_out;

    // ---- workspace layout (disjoint; ~113 MiB total) ----
    char* wsb = (char*)d_ws;
    int*   counts     = (int*)(wsb + 0);
    int*   offsets    = (int*)(wsb + 256);
    int*   topk_id    = (int*)(wsb + 4096);
    float* topk_w     = (float*)(wsb + 20480);
    int*   sorted_tok = (int*)(wsb + 36864);
    float* row_w      = (float*)(wsb + 53248);
    unsigned short* xb    = (unsigned short*)(wsb + (1u << 20));   // 8 MiB
    unsigned short* actb  = (unsigned short*)(wsb + 9437184);      // 8 MiB
    unsigned short* wsb16 = (unsigned short*)(wsb + 17825792);     // 64 MiB
    unsigned short* w2b   = (unsigned short*)(wsb + 84934656);     // 32 MiB

    hipMemsetAsync(out, 0, (size_t)out_size * sizeof(float), stream);
    prep_kernel<<<4096, 256, 0, stream>>>(ws, w2s, x, gw, wsb16, w2b, xb, topk_id, topk_w);
    sort_kernel<<<1, 512, 0, stream>>>(topk_id, topk_w, sorted_tok, row_w, offsets, counts);
    gemm1_kernel<<<2048, 512, 0, stream>>>(wsb16, xb, offsets, counts, sorted_tok, actb);
    gemm2_kernel<<<2048, 512, 0, stream>>>(w2b, actb, offsets, counts, sorted_tok, row_w, out);
}